// Round 9
// baseline (1322.216 us; speedup 1.0000x reference)
//
#include <hip/hip_runtime.h>
#include <math.h>

#define NN 50000      // nodes
#define GG 100        // graphs
#define NPGc 500      // nodes per graph
#define HH 256        // hidden
#define IND 128       // input dim

typedef __attribute__((ext_vector_type(8))) short short8v;  // 8 bf16
typedef __attribute__((ext_vector_type(4))) float f32x4;

__device__ __forceinline__ ushort f2bf(float f) {
    union { float f; unsigned u; } v; v.f = f;
    unsigned r = (v.u + 0x7fffu + ((v.u >> 16) & 1u)) >> 16;  // RNE
    return (ushort)r;
}
__device__ __forceinline__ float bf2f(ushort h) {
    union { unsigned u; float f; } v; v.u = ((unsigned)h) << 16;
    return v.f;
}

// LDS ushort-index swizzle: XOR 16B-granule bits with row&7 (T2, bank-conflict fix)
__device__ __forceinline__ int swz(int row, int kidx) { return kidx ^ ((row & 7) << 3); }

// ---------------------------------------------------------------------------
// Weight transpose+convert: src [K][N] f32 -> dst [N][K] bf16
// ---------------------------------------------------------------------------
__global__ void wcvt(const float* __restrict__ src, ushort* __restrict__ dst, int K, int N)
{
    int i = blockIdx.x * 256 + threadIdx.x;
    if (i < K * N) {
        int n = i / K, k = i % K;
        dst[i] = f2bf(src[(size_t)k * N + n]);
    }
}

// ---------------------------------------------------------------------------
// bf16 MFMA GEMM: C[M x 256] = A[M x K](f32, cvt on stage) @ Wt[N=256][K](bf16)
// tile 128x128, BK=64, 4 waves each 64x64. LDS XOR-swizzled.
// mode 0: C=f32 acc(+bias). mode 1: gate epilogue. mode 2: Cbf=bf16 acc(+bias).
// ---------------------------------------------------------------------------
__global__ __launch_bounds__(256)
void gemm_mfma(const float* __restrict__ A, const float* __restrict__ A2,
               const ushort* __restrict__ Wt, const float* __restrict__ bias,
               float* __restrict__ C, ushort* __restrict__ Cbf,
               int M, int K, int lda, int mode,
               const float* __restrict__ hn, const float* __restrict__ fn,
               const float* __restrict__ prev)
{
    __shared__ ushort As[128][64];
    __shared__ ushort Bs[128][64];
    const int tid = threadIdx.x;
    const int lane = tid & 63;
    const int w = tid >> 6;
    const int wr = (w >> 1) * 64, wc = (w & 1) * 64;
    const int row0 = blockIdx.x * 128, col0 = blockIdx.y * 128;
    const int lr = lane & 15, lk = (lane >> 4) * 8;
    f32x4 acc[4][4] = {};

    for (int k0 = 0; k0 < K; k0 += 64) {
        __syncthreads();
        #pragma unroll
        for (int it = 0; it < 4; ++it) {           // stage A: 128x64, f32->bf16
            int c = it * 256 + tid;
            int row = c >> 3, col = (c & 7) * 8;
            int gr = row0 + row; if (gr > M - 1) gr = M - 1;
            const float* Ap = A; int kk = k0 + col;
            if (A2 != nullptr && kk >= 256) { Ap = A2; kk -= 256; }
            const float* s = &Ap[(size_t)gr * lda + kk];
            float4 v0 = *(const float4*)s;
            float4 v1 = *(const float4*)(s + 4);
            union { ushort u[8]; int4 q; } pk;
            pk.u[0] = f2bf(v0.x); pk.u[1] = f2bf(v0.y); pk.u[2] = f2bf(v0.z); pk.u[3] = f2bf(v0.w);
            pk.u[4] = f2bf(v1.x); pk.u[5] = f2bf(v1.y); pk.u[6] = f2bf(v1.z); pk.u[7] = f2bf(v1.w);
            *(int4*)&As[row][swz(row, col)] = pk.q;
        }
        #pragma unroll
        for (int it = 0; it < 4; ++it) {           // stage B: Wt rows col0..+127
            int c = it * 256 + tid;
            int n = c >> 3, k = (c & 7) * 8;
            *(int4*)&Bs[n][swz(n, k)] = *(const int4*)&Wt[(size_t)(col0 + n) * K + k0 + k];
        }
        __syncthreads();
        #pragma unroll
        for (int ks = 0; ks < 2; ++ks) {
            short8v av[4], bv[4];
            #pragma unroll
            for (int m = 0; m < 4; ++m) {
                int rr = wr + m * 16 + lr;
                av[m] = *(const short8v*)&As[rr][swz(rr, ks * 32 + lk)];
            }
            #pragma unroll
            for (int n = 0; n < 4; ++n) {
                int rr = wc + n * 16 + lr;
                bv[n] = *(const short8v*)&Bs[rr][swz(rr, ks * 32 + lk)];
            }
            #pragma unroll
            for (int m = 0; m < 4; ++m)
                #pragma unroll
                for (int n = 0; n < 4; ++n)
                    acc[m][n] = __builtin_amdgcn_mfma_f32_16x16x32_bf16(av[m], bv[n], acc[m][n], 0, 0, 0);
        }
    }
    const int fr = (lane >> 4) * 4;
    if (mode == 0) {
        #pragma unroll
        for (int n = 0; n < 4; ++n) {
            int col = col0 + wc + n * 16 + lr;
            float bb = bias ? bias[col] : 0.f;
            #pragma unroll
            for (int m = 0; m < 4; ++m) {
                int rbase = row0 + wr + m * 16 + fr;
                #pragma unroll
                for (int r = 0; r < 4; ++r) {
                    int row = rbase + r;
                    if (row < M) C[(size_t)row * HH + col] = acc[m][n][r] + bb;
                }
            }
        }
    } else if (mode == 2) {
        #pragma unroll
        for (int n = 0; n < 4; ++n) {
            int col = col0 + wc + n * 16 + lr;
            float bb = bias ? bias[col] : 0.f;
            #pragma unroll
            for (int m = 0; m < 4; ++m) {
                int rbase = row0 + wr + m * 16 + fr;
                #pragma unroll
                for (int r = 0; r < 4; ++r) {
                    int row = rbase + r;
                    if (row < M) Cbf[(size_t)row * HH + col] = f2bf(acc[m][n][r] + bb);
                }
            }
        }
    } else {
        #pragma unroll
        for (int n = 0; n < 4; ++n) {
            int col = col0 + wc + n * 16 + lr;
            float gb = bias[col];
            #pragma unroll
            for (int m = 0; m < 4; ++m) {
                int rbase = row0 + wr + m * 16 + fr;
                #pragma unroll
                for (int r = 0; r < 4; ++r) {
                    int row = rbase + r;
                    if (row < M) {
                        size_t o = (size_t)row * HH + col;
                        float z = acc[m][n][r] + gb;
                        float s = 1.f / (1.f + expf(-z));
                        C[o] = s * hn[o] + (1.f - s) * fn[o] + prev[o];
                    }
                }
            }
        }
    }
}

// ---------------------------------------------------------------------------
// Row L2-normalize, emit bf16 hi/lo split
// ---------------------------------------------------------------------------
__global__ __launch_bounds__(256)
void row_norm_hl(const float* __restrict__ h, ushort* __restrict__ xh, ushort* __restrict__ xl)
{
    int n = blockIdx.x, c = threadIdx.x;
    float v = h[(size_t)n * HH + c];
    __shared__ float red[256];
    red[c] = v * v;
    __syncthreads();
    for (int s = 128; s > 0; s >>= 1) {
        if (c < s) red[c] += red[c + s];
        __syncthreads();
    }
    float norm = sqrtf(red[0]);
    float xn = v / (norm + 1e-12f);
    ushort hi = f2bf(xn);
    xh[(size_t)n * HH + c] = hi;
    xl[(size_t)n * HH + c] = f2bf(xn - bf2f(hi));
}

// ---------------------------------------------------------------------------
// top-3 helpers (exact top_k tie-breaking: value desc, index asc)
// ---------------------------------------------------------------------------
__device__ __forceinline__ bool tk_better(float va, int ia, float vb, int ib)
{
    return (va > vb) || (va == vb && ia < ib);
}

__device__ __forceinline__ void ins3(float v, int i,
                                     float& a0, int& b0, float& a1, int& b1,
                                     float& a2, int& b2)
{
    if (tk_better(v, i, a0, b0))      { a2 = a1; b2 = b1; a1 = a0; b1 = b0; a0 = v; b0 = i; }
    else if (tk_better(v, i, a1, b1)) { a2 = a1; b2 = b1; a1 = v;  b1 = i; }
    else if (tk_better(v, i, a2, b2)) { a2 = v;  b2 = i; }
}

__device__ __forceinline__ void merge3(float& v0, float& v1, float& v2,
                                       int& i0, int& i1, int& i2, int off)
{
    float w0 = __shfl_xor(v0, off), w1 = __shfl_xor(v1, off), w2 = __shfl_xor(v2, off);
    int   j0 = __shfl_xor(i0, off), j1 = __shfl_xor(i1, off), j2 = __shfl_xor(i2, off);
    float avv[3] = { v0, v1, v2 }, bvv[3] = { w0, w1, w2 };
    int   aii[3] = { i0, i1, i2 }, bii[3] = { j0, j1, j2 };
    float rv[3]; int ri[3];
    int p = 0, q = 0;
    #pragma unroll
    for (int t = 0; t < 3; ++t) {
        bool takeA = tk_better(avv[p], aii[p], bvv[q], bii[q]);
        rv[t] = takeA ? avv[p] : bvv[q];
        ri[t] = takeA ? aii[p] : bii[q];
        if (takeA) ++p; else ++q;
    }
    v0 = rv[0]; v1 = rv[1]; v2 = rv[2];
    i0 = ri[0]; i1 = ri[1]; i2 = ri[2];
}

// ---------------------------------------------------------------------------
// simtopk v4: LOW register pressure (anti-spill rewrite).
// Block = 64 rows of one graph, 4 waves; wave owns 16 rows x 128 cols
// (acc[8] = 32 VGPR only). A AND B both staged in LDS per (ct,k0) tile;
// operands read 2-at-a-time inside the n loop (transient). Top-3 fold and
// merge operate on scalar locals. Peak live regs ~90 -> no scratch.
// XCD-swizzled grid: 8 row-blocks of a graph share one XCD residue.
// ---------------------------------------------------------------------------
__global__ __launch_bounds__(256, 2)
void simtopk(const ushort* __restrict__ xnh, const ushort* __restrict__ xnl,
             int* __restrict__ fsrc)
{
    __shared__ ushort Ash[64][64], Asl[64][64];     // 16 KB
    __shared__ ushort Bsh[128][64], Bsl[128][64];   // 32 KB
    const int bid = blockIdx.x;
    const int xcd = bid & 7;
    const int rb  = (bid >> 3) & 7;
    const int g   = (bid >> 6) * 8 + xcd;
    if (g >= GG) return;
    const int row0 = rb * 64;
    const int tid  = threadIdx.x;
    const int lane = tid & 63;
    const int w    = tid >> 6;
    const int lr   = lane & 15;
    const int hi4  = lane >> 4;
    const int lk   = hi4 * 8;
    const size_t base = (size_t)g * NPGc * HH;

    // running top-3 per acc row r: rows row0 + w*16 + hi4*4 + r
    float tv0[4], tv1[4], tv2[4];
    int   ti0[4], ti1[4], ti2[4];
    #pragma unroll
    for (int r = 0; r < 4; ++r) {
        tv0[r] = tv1[r] = tv2[r] = -2.f;
        ti0[r] = ti1[r] = ti2[r] = 0x7fffffff;
    }

    for (int ct = 0; ct < 4; ++ct) {
        const int col0 = ct * 128;
        f32x4 acc[8] = {};
        for (int k0 = 0; k0 < HH; k0 += 64) {
            __syncthreads();
            #pragma unroll
            for (int it = 0; it < 2; ++it) {       // stage A: 64 rows x 64 k
                int flat = it * 256 + tid;
                int row = flat >> 3, col = (flat & 7) * 8;
                int grow = row0 + row; if (grow > NPGc - 1) grow = NPGc - 1;
                size_t o = base + (size_t)grow * HH + k0 + col;
                *(int4*)&Ash[row][swz(row, col)] = *(const int4*)(xnh + o);
                *(int4*)&Asl[row][swz(row, col)] = *(const int4*)(xnl + o);
            }
            #pragma unroll
            for (int it = 0; it < 4; ++it) {       // stage B: 128 cols x 64 k
                int flat = it * 256 + tid;
                int row = flat >> 3, col = (flat & 7) * 8;
                int gcol = col0 + row; if (gcol > NPGc - 1) gcol = NPGc - 1;
                size_t o = base + (size_t)gcol * HH + k0 + col;
                *(int4*)&Bsh[row][swz(row, col)] = *(const int4*)(xnh + o);
                *(int4*)&Bsl[row][swz(row, col)] = *(const int4*)(xnl + o);
            }
            __syncthreads();
            #pragma unroll
            for (int ks = 0; ks < 2; ++ks) {
                const int ra = w * 16 + lr;
                short8v ah = *(const short8v*)&Ash[ra][swz(ra, ks * 32 + lk)];
                short8v al = *(const short8v*)&Asl[ra][swz(ra, ks * 32 + lk)];
                #pragma unroll
                for (int n = 0; n < 8; ++n) {
                    const int rbn = n * 16 + lr;
                    short8v bh = *(const short8v*)&Bsh[rbn][swz(rbn, ks * 32 + lk)];
                    short8v bl = *(const short8v*)&Bsl[rbn][swz(rbn, ks * 32 + lk)];
                    acc[n] = __builtin_amdgcn_mfma_f32_16x16x32_bf16(ah, bh, acc[n], 0, 0, 0);
                    acc[n] = __builtin_amdgcn_mfma_f32_16x16x32_bf16(ah, bl, acc[n], 0, 0, 0);
                    acc[n] = __builtin_amdgcn_mfma_f32_16x16x32_bf16(al, bh, acc[n], 0, 0, 0);
                }
            }
        }
        // fold this col-tile into running top-3, scalar locals per row r
        #pragma unroll
        for (int r = 0; r < 4; ++r) {
            float a0 = tv0[r], a1 = tv1[r], a2 = tv2[r];
            int   b0 = ti0[r], b1 = ti1[r], b2 = ti2[r];
            #pragma unroll
            for (int n = 0; n < 8; ++n) {
                int col = col0 + n * 16 + lr;
                if (col < NPGc)
                    ins3(acc[n][r], col, a0, b0, a1, b1, a2, b2);
            }
            tv0[r] = a0; tv1[r] = a1; tv2[r] = a2;
            ti0[r] = b0; ti1[r] = b1; ti2[r] = b2;
        }
    }

    // merge across the 16 lanes sharing each row-quad (xor 1,2,4,8), then write
    #pragma unroll
    for (int r = 0; r < 4; ++r) {
        float a0 = tv0[r], a1 = tv1[r], a2 = tv2[r];
        int   b0 = ti0[r], b1 = ti1[r], b2 = ti2[r];
        #pragma unroll
        for (int off = 1; off <= 8; off <<= 1)
            merge3(a0, a1, a2, b0, b1, b2, off);
        if (lr == 0) {
            int row = row0 + w * 16 + hi4 * 4 + r;
            if (row < NPGc) {
                int rg = g * NPGc + row;
                fsrc[rg * 3 + 0] = g * NPGc + b0;
                fsrc[rg * 3 + 1] = g * NPGc + b1;
                fsrc[rg * 3 + 2] = g * NPGc + b2;
            }
        }
    }
}

// ---------------------------------------------------------------------------
// CSR build
// ---------------------------------------------------------------------------
__global__ void hist_kernel(const int* __restrict__ dst, int* __restrict__ cnt, int nE)
{
    int e = blockIdx.x * 256 + threadIdx.x;
    if (e < nE) atomicAdd(&cnt[dst[e]], 1);
}

__global__ void scan1_kernel(const int* __restrict__ in, int* __restrict__ out,
                             int* __restrict__ bsum, int n)
{
    __shared__ int sh[256];
    int t = threadIdx.x;
    int i = blockIdx.x * 256 + t;
    int v = (i < n) ? in[i] : 0;
    sh[t] = v;
    __syncthreads();
    for (int s = 1; s < 256; s <<= 1) {
        int tv = (t >= s) ? sh[t - s] : 0;
        __syncthreads();
        sh[t] += tv;
        __syncthreads();
    }
    if (i < n) out[i] = sh[t] - v;  // exclusive
    if (t == 255) bsum[blockIdx.x] = sh[255];
}

__global__ void scan2_kernel(int* __restrict__ bsum, int nb)
{
    __shared__ int sh[256];
    int t = threadIdx.x;
    int v = (t < nb) ? bsum[t] : 0;
    sh[t] = v;
    __syncthreads();
    for (int s = 1; s < 256; s <<= 1) {
        int tv = (t >= s) ? sh[t - s] : 0;
        __syncthreads();
        sh[t] += tv;
        __syncthreads();
    }
    if (t < nb) bsum[t] = sh[t] - v;  // exclusive block offsets
}

__global__ void scan3_kernel(int* __restrict__ out, const int* __restrict__ bsum, int n)
{
    int i = blockIdx.x * 256 + threadIdx.x;
    if (i < n) out[i] += bsum[blockIdx.x];
}

__global__ void fill_kernel(const int* __restrict__ src, const int* __restrict__ dst,
                            const int* __restrict__ row_ptr, int* __restrict__ cursor,
                            int* __restrict__ sorted_src, int nE)
{
    int e = blockIdx.x * 256 + threadIdx.x;
    if (e < nE) {
        int d = dst[e];
        int pos = row_ptr[d] + atomicAdd(&cursor[d], 1);
        sorted_src[pos] = src[e];
    }
}

__global__ void dinv_kernel(const int* __restrict__ cnt, float* __restrict__ dinv, int n)
{
    int i = blockIdx.x * 256 + threadIdx.x;
    if (i < n) dinv[i] = rsqrtf((float)cnt[i] + 1.0f);
}

// ---------------------------------------------------------------------------
// GCN gather (bf16 messages, XCD-bijective swizzle: graph g -> XCD g%8)
// grid = 8 * 13 * 500 = 52000, blocks with g >= 100 exit.
// ---------------------------------------------------------------------------
__global__ __launch_bounds__(256)
void gcn_gather(const ushort* __restrict__ m, const int* __restrict__ row_ptr,
                const int* __restrict__ cnt, const int* __restrict__ srcs,
                const float* __restrict__ dinv, const float* __restrict__ bias,
                float* __restrict__ out)
{
    int bid = blockIdx.x;
    int xcd = bid & 7, idx = bid >> 3;
    int g = xcd + 8 * (idx / NPGc);
    if (g >= GG) return;
    int n = g * NPGc + (idx % NPGc);
    int c = threadIdx.x;
    float dn = dinv[n];
    float acc = bf2f(m[(size_t)n * HH + c]) * dn;
    int s0 = row_ptr[n], e0 = s0 + cnt[n];
    for (int e = s0; e < e0; ++e) {
        int s = srcs[e];
        acc += bf2f(m[(size_t)s * HH + c]) * dinv[s];
    }
    out[(size_t)n * HH + c] = acc * dn + bias[c];
}

// knn-graph conv: all degrees are K+1=4 -> coef = 0.25 everywhere
__global__ __launch_bounds__(256)
void fgcn_gather(const ushort* __restrict__ m, const int* __restrict__ fsrc,
                 const float* __restrict__ bias, float* __restrict__ out)
{
    int bid = blockIdx.x;
    int xcd = bid & 7, idx = bid >> 3;
    int g = xcd + 8 * (idx / NPGc);
    if (g >= GG) return;
    int n = g * NPGc + (idx % NPGc);
    int c = threadIdx.x;
    int s0 = fsrc[n * 3], s1 = fsrc[n * 3 + 1], s2 = fsrc[n * 3 + 2];
    float acc = bf2f(m[(size_t)n * HH + c]) + bf2f(m[(size_t)s0 * HH + c])
              + bf2f(m[(size_t)s1 * HH + c]) + bf2f(m[(size_t)s2 * HH + c]);
    out[(size_t)n * HH + c] = 0.25f * acc + bias[c];
}

// ---------------------------------------------------------------------------
// GraphNorm
// ---------------------------------------------------------------------------
__global__ __launch_bounds__(256)
void norm_stats(const float* __restrict__ x, float* __restrict__ S1, float* __restrict__ S2)
{
    int g = blockIdx.x, chunk = blockIdx.y, c = threadIdx.x;
    int r0 = chunk * 63, r1 = min(r0 + 63, NPGc);
    float s1 = 0.f, s2 = 0.f;
    for (int r = r0; r < r1; ++r) {
        float v = x[((size_t)(g * NPGc + r)) * HH + c];
        s1 += v; s2 += v * v;
    }
    atomicAdd(&S1[g * HH + c], s1);
    atomicAdd(&S2[g * HH + c], s2);
}

__global__ __launch_bounds__(256)
void norm_apply(float* __restrict__ x, const float* __restrict__ S1, const float* __restrict__ S2,
                const float* __restrict__ w, const float* __restrict__ b,
                const float* __restrict__ ms)
{
    int n = blockIdx.x, c = threadIdx.x;
    int g = n / NPGc;
    size_t o = (size_t)n * HH + c;
    float v = x[o];
    float mean = S1[g * HH + c] / (float)NPGc;
    float mm = mean * ms[c];
    float var = S2[g * HH + c] / (float)NPGc - 2.f * mm * mean + mm * mm;
    float outv = w[c] * (v - mm) * rsqrtf(var + 1e-5f) + b[c];
    x[o] = outv > 0.f ? outv : 0.01f * outv;
}

// ---------------------------------------------------------------------------
// Pool: gf[g] = (sum X0 + 2*sum X1) / 500   (all_x[-1]==all_x[1] quirk)
// ---------------------------------------------------------------------------
__global__ __launch_bounds__(256)
void pool_kernel(const float* __restrict__ X0, const float* __restrict__ X1,
                 float* __restrict__ out)
{
    int g = blockIdx.x, c = threadIdx.x;
    float s0 = 0.f, s1 = 0.f;
    for (int r = 0; r < NPGc; ++r) {
        size_t o = ((size_t)(g * NPGc + r)) * HH + c;
        s0 += X0[o];
        s1 += X1[o];
    }
    out[g * HH + c] = (s0 + 2.f * s1) / (float)NPGc;
}

__global__ void sentinel_kernel(float* out, int n)
{
    int i = blockIdx.x * 256 + threadIdx.x;
    if (i < n) out[i] = 12345.0f;
}

// ---------------------------------------------------------------------------
extern "C" void kernel_launch(void* const* d_in, const int* in_sizes, int n_in,
                              void* d_out, int out_size, void* d_ws, size_t ws_size,
                              hipStream_t stream)
{
    const float* x       = (const float*)d_in[0];
    const int* edge_idx  = (const int*)d_in[1];
    const float* emb_W   = (const float*)d_in[3];
    const float* emb_b   = (const float*)d_in[4];
    const float* conv_W  = (const float*)d_in[5];
    const float* conv_b  = (const float*)d_in[6];
    const float* fconv_W = (const float*)d_in[7];
    const float* fconv_b = (const float*)d_in[8];
    const float* norm_w  = (const float*)d_in[9];
    const float* norm_b  = (const float*)d_in[10];
    const float* norm_ms = (const float*)d_in[11];
    const float* fnorm_w = (const float*)d_in[12];
    const float* fnorm_b = (const float*)d_in[13];
    const float* fnorm_ms= (const float*)d_in[14];
    const float* gate_W  = (const float*)d_in[15];
    const float* gate_b  = (const float*)d_in[16];

    const int E = in_sizes[1] / 2;
    const int* esrc = edge_idx;
    const int* edst = edge_idx + E;

    const size_t NHf = (size_t)NN * HH;           // 12.8M elements
    char* p = (char*)d_ws;
    auto alloc = [&](size_t bytes) { char* r = p; p += (bytes + 255) & ~(size_t)255; return r; };
    float* B0 = (float*)alloc(NHf * 4);
    float* B1 = (float*)alloc(NHf * 4);
    float* B2 = (float*)alloc(NHf * 4);
    float* B3 = (float*)alloc(NHf * 4);
    ushort* xnh = (ushort*)B2;          // 25.6MB overlay, dead once layers start
    ushort* xnl = xnh + NHf;            // 25.6MB (rest of B2)
    ushort* msgbf = (ushort*)alloc(NHf * 2);  // bf16 message buffer
    int* sorted_src = (int*)alloc((size_t)E * 4);
    int* row_ptr    = (int*)alloc((size_t)NN * 4);
    int* deg_cnt    = (int*)alloc((size_t)NN * 4);
    int* cursor     = (int*)alloc((size_t)NN * 4);
    float* dinv     = (float*)alloc((size_t)NN * 4);
    int* fsrc       = (int*)alloc((size_t)NN * 3 * 4);
    float* S1       = (float*)alloc((size_t)GG * HH * 4);
    float* S2       = (float*)alloc((size_t)GG * HH * 4);
    int* bsum       = (int*)alloc(1024);
    ushort* wts     = (ushort*)alloc((size_t)425984 * 2);  // all W^T bf16
    size_t needed = (size_t)(p - (char*)d_ws);
    if (ws_size < needed) {
        sentinel_kernel<<<(out_size + 255) / 256, 256, 0, stream>>>((float*)d_out, out_size);
        return;
    }
    ushort* embWt   = wts;                    // [256][128]
    ushort* convWt0 = wts + 32768;            // [256][256]
    ushort* convWt1 = wts + 32768 + 65536;
    ushort* fconvWt0 = wts + 163840;
    ushort* fconvWt1 = wts + 163840 + 65536;
    ushort* gateWt  = wts + 294912;           // [256][512]

    const int nScanB = (NN + 255) / 256;  // 196
    const int gatherGrid = 8 * 13 * NPGc; // 52000 (XCD-bijective, skip g>=100)

    hipMemsetAsync(deg_cnt, 0, (size_t)NN * 4, stream);
    hipMemsetAsync(cursor, 0, (size_t)NN * 4, stream);

    // 0. weight transpose+cvt
    wcvt<<<(32768 + 255) / 256, 256, 0, stream>>>(emb_W, embWt, IND, HH);
    wcvt<<<(65536 + 255) / 256, 256, 0, stream>>>(conv_W, convWt0, HH, HH);
    wcvt<<<(65536 + 255) / 256, 256, 0, stream>>>(conv_W + 65536, convWt1, HH, HH);
    wcvt<<<(65536 + 255) / 256, 256, 0, stream>>>(fconv_W, fconvWt0, HH, HH);
    wcvt<<<(65536 + 255) / 256, 256, 0, stream>>>(fconv_W + 65536, fconvWt1, HH, HH);
    wcvt<<<(131072 + 255) / 256, 256, 0, stream>>>(gate_W, gateWt, 2 * HH, HH);

    // 1. embedding: h0 = x @ emb_W + emb_b -> B0
    dim3 ggrid((NN + 127) / 128, 2);
    gemm_mfma<<<ggrid, 256, 0, stream>>>(x, nullptr, embWt, emb_b, B0, nullptr,
                                         NN, IND, IND, 0, nullptr, nullptr, nullptr);

    // 2. CSR of edge_index by dst
    hist_kernel<<<(E + 255) / 256, 256, 0, stream>>>(edst, deg_cnt, E);
    scan1_kernel<<<nScanB, 256, 0, stream>>>(deg_cnt, row_ptr, bsum, NN);
    scan2_kernel<<<1, 256, 0, stream>>>(bsum, nScanB);
    scan3_kernel<<<nScanB, 256, 0, stream>>>(row_ptr, bsum, NN);
    fill_kernel<<<(E + 255) / 256, 256, 0, stream>>>(esrc, edst, row_ptr, cursor, sorted_src, E);
    dinv_kernel<<<(NN + 255) / 256, 256, 0, stream>>>(deg_cnt, dinv, NN);

    // 3. knn graph from h0 (hi/lo split, low-pressure fused sim+topk)
    row_norm_hl<<<NN, 256, 0, stream>>>(B0, xnh, xnl);
    simtopk<<<832, 256, 0, stream>>>(xnh, xnl, fsrc);

    // 4. layers
    float* h  = B0;
    float* mb = B1;
    dim3 ngrid(GG, 8);
    for (int i = 0; i < 2; ++i) {
        const ushort* Wc = (i == 0) ? convWt0 : convWt1;
        const ushort* Wf = (i == 0) ? fconvWt0 : fconvWt1;
        const float* bc  = conv_b  + (size_t)i * HH;
        const float* bf  = fconv_b + (size_t)i * HH;
        // h-road conv -> bf16 messages
        gemm_mfma<<<ggrid, 256, 0, stream>>>(h, nullptr, Wc, nullptr, nullptr, msgbf,
                                             NN, HH, HH, 2, nullptr, nullptr, nullptr);
        gcn_gather<<<gatherGrid, 256, 0, stream>>>(msgbf, row_ptr, deg_cnt, sorted_src,
                                                   dinv, bc, B2);
        hipMemsetAsync(S1, 0, (size_t)2 * GG * HH * 4, stream);
        norm_stats<<<ngrid, 256, 0, stream>>>(B2, S1, S2);
        norm_apply<<<NN, 256, 0, stream>>>(B2, S1, S2, norm_w + i * HH, norm_b + i * HH,
                                           norm_ms + i * HH);
        // f-road conv (knn graph) -> bf16 messages
        gemm_mfma<<<ggrid, 256, 0, stream>>>(B2, nullptr, Wf, nullptr, nullptr, msgbf,
                                             NN, HH, HH, 2, nullptr, nullptr, nullptr);
        fgcn_gather<<<gatherGrid, 256, 0, stream>>>(msgbf, fsrc, bf, B3);
        hipMemsetAsync(S1, 0, (size_t)2 * GG * HH * 4, stream);
        norm_stats<<<ngrid, 256, 0, stream>>>(B3, S1, S2);
        norm_apply<<<NN, 256, 0, stream>>>(B3, S1, S2, fnorm_w + i * HH, fnorm_b + i * HH,
                                           fnorm_ms + i * HH);
        // gate + combine
        gemm_mfma<<<ggrid, 256, 0, stream>>>(B2, B3, gateWt, gate_b, mb, nullptr,
                                             NN, 2 * HH, HH, 1, B2, B3, h);
        float* t = h; h = mb; mb = t;
    }
    // h = all_x[1], mb = all_x[0]
    pool_kernel<<<GG, 256, 0, stream>>>(mb, h, (float*)d_out);
}

// Round 10
// 1299.584 us; speedup vs baseline: 1.0174x; 1.0174x over previous
//
#include <hip/hip_runtime.h>
#include <math.h>

#define NN 50000      // nodes
#define GG 100        // graphs
#define NPGc 500      // nodes per graph
#define HH 256        // hidden
#define IND 128       // input dim

typedef __attribute__((ext_vector_type(8))) short short8v;  // 8 bf16
typedef __attribute__((ext_vector_type(4))) float f32x4;

__device__ __forceinline__ ushort f2bf(float f) {
    union { float f; unsigned u; } v; v.f = f;
    unsigned r = (v.u + 0x7fffu + ((v.u >> 16) & 1u)) >> 16;  // RNE
    return (ushort)r;
}
__device__ __forceinline__ float bf2f(ushort h) {
    union { unsigned u; float f; } v; v.u = ((unsigned)h) << 16;
    return v.f;
}

// LDS ushort-index swizzle: XOR 16B-granule bits with row&7 (T2, bank-conflict fix)
__device__ __forceinline__ int swz(int row, int kidx) { return kidx ^ ((row & 7) << 3); }

// ---------------------------------------------------------------------------
// Weight transpose+convert: src [K][N] f32 -> dst [N][K] bf16
// ---------------------------------------------------------------------------
__global__ void wcvt(const float* __restrict__ src, ushort* __restrict__ dst, int K, int N)
{
    int i = blockIdx.x * 256 + threadIdx.x;
    if (i < K * N) {
        int n = i / K, k = i % K;
        dst[i] = f2bf(src[(size_t)k * N + n]);
    }
}

// ---------------------------------------------------------------------------
// bf16 MFMA GEMM: C[M x 256] = A[M x K](f32, cvt on stage) @ Wt[N=256][K](bf16)
// tile 128x128, BK=64, 4 waves each 64x64. LDS XOR-swizzled.
// mode 0: C=f32 acc(+bias). mode 1: gate epilogue. mode 2: Cbf=bf16 acc(+bias).
// ---------------------------------------------------------------------------
__global__ __launch_bounds__(256)
void gemm_mfma(const float* __restrict__ A, const float* __restrict__ A2,
               const ushort* __restrict__ Wt, const float* __restrict__ bias,
               float* __restrict__ C, ushort* __restrict__ Cbf,
               int M, int K, int lda, int mode,
               const float* __restrict__ hn, const float* __restrict__ fn,
               const float* __restrict__ prev)
{
    __shared__ ushort As[128][64];
    __shared__ ushort Bs[128][64];
    const int tid = threadIdx.x;
    const int lane = tid & 63;
    const int w = tid >> 6;
    const int wr = (w >> 1) * 64, wc = (w & 1) * 64;
    const int row0 = blockIdx.x * 128, col0 = blockIdx.y * 128;
    const int lr = lane & 15, lk = (lane >> 4) * 8;
    f32x4 acc[4][4] = {};

    for (int k0 = 0; k0 < K; k0 += 64) {
        __syncthreads();
        #pragma unroll
        for (int it = 0; it < 4; ++it) {           // stage A: 128x64, f32->bf16
            int c = it * 256 + tid;
            int row = c >> 3, col = (c & 7) * 8;
            int gr = row0 + row; if (gr > M - 1) gr = M - 1;
            const float* Ap = A; int kk = k0 + col;
            if (A2 != nullptr && kk >= 256) { Ap = A2; kk -= 256; }
            const float* s = &Ap[(size_t)gr * lda + kk];
            float4 v0 = *(const float4*)s;
            float4 v1 = *(const float4*)(s + 4);
            union { ushort u[8]; int4 q; } pk;
            pk.u[0] = f2bf(v0.x); pk.u[1] = f2bf(v0.y); pk.u[2] = f2bf(v0.z); pk.u[3] = f2bf(v0.w);
            pk.u[4] = f2bf(v1.x); pk.u[5] = f2bf(v1.y); pk.u[6] = f2bf(v1.z); pk.u[7] = f2bf(v1.w);
            *(int4*)&As[row][swz(row, col)] = pk.q;
        }
        #pragma unroll
        for (int it = 0; it < 4; ++it) {           // stage B: Wt rows col0..+127
            int c = it * 256 + tid;
            int n = c >> 3, k = (c & 7) * 8;
            *(int4*)&Bs[n][swz(n, k)] = *(const int4*)&Wt[(size_t)(col0 + n) * K + k0 + k];
        }
        __syncthreads();
        #pragma unroll
        for (int ks = 0; ks < 2; ++ks) {
            short8v av[4], bv[4];
            #pragma unroll
            for (int m = 0; m < 4; ++m) {
                int rr = wr + m * 16 + lr;
                av[m] = *(const short8v*)&As[rr][swz(rr, ks * 32 + lk)];
            }
            #pragma unroll
            for (int n = 0; n < 4; ++n) {
                int rr = wc + n * 16 + lr;
                bv[n] = *(const short8v*)&Bs[rr][swz(rr, ks * 32 + lk)];
            }
            #pragma unroll
            for (int m = 0; m < 4; ++m)
                #pragma unroll
                for (int n = 0; n < 4; ++n)
                    acc[m][n] = __builtin_amdgcn_mfma_f32_16x16x32_bf16(av[m], bv[n], acc[m][n], 0, 0, 0);
        }
    }
    const int fr = (lane >> 4) * 4;
    if (mode == 0) {
        #pragma unroll
        for (int n = 0; n < 4; ++n) {
            int col = col0 + wc + n * 16 + lr;
            float bb = bias ? bias[col] : 0.f;
            #pragma unroll
            for (int m = 0; m < 4; ++m) {
                int rbase = row0 + wr + m * 16 + fr;
                #pragma unroll
                for (int r = 0; r < 4; ++r) {
                    int row = rbase + r;
                    if (row < M) C[(size_t)row * HH + col] = acc[m][n][r] + bb;
                }
            }
        }
    } else if (mode == 2) {
        #pragma unroll
        for (int n = 0; n < 4; ++n) {
            int col = col0 + wc + n * 16 + lr;
            float bb = bias ? bias[col] : 0.f;
            #pragma unroll
            for (int m = 0; m < 4; ++m) {
                int rbase = row0 + wr + m * 16 + fr;
                #pragma unroll
                for (int r = 0; r < 4; ++r) {
                    int row = rbase + r;
                    if (row < M) Cbf[(size_t)row * HH + col] = f2bf(acc[m][n][r] + bb);
                }
            }
        }
    } else {
        #pragma unroll
        for (int n = 0; n < 4; ++n) {
            int col = col0 + wc + n * 16 + lr;
            float gb = bias[col];
            #pragma unroll
            for (int m = 0; m < 4; ++m) {
                int rbase = row0 + wr + m * 16 + fr;
                #pragma unroll
                for (int r = 0; r < 4; ++r) {
                    int row = rbase + r;
                    if (row < M) {
                        size_t o = (size_t)row * HH + col;
                        float z = acc[m][n][r] + gb;
                        float s = 1.f / (1.f + expf(-z));
                        C[o] = s * hn[o] + (1.f - s) * fn[o] + prev[o];
                    }
                }
            }
        }
    }
}

// ---------------------------------------------------------------------------
// Row L2-normalize, emit bf16 hi/lo split
// ---------------------------------------------------------------------------
__global__ __launch_bounds__(256)
void row_norm_hl(const float* __restrict__ h, ushort* __restrict__ xh, ushort* __restrict__ xl)
{
    int n = blockIdx.x, c = threadIdx.x;
    float v = h[(size_t)n * HH + c];
    __shared__ float red[256];
    red[c] = v * v;
    __syncthreads();
    for (int s = 128; s > 0; s >>= 1) {
        if (c < s) red[c] += red[c + s];
        __syncthreads();
    }
    float norm = sqrtf(red[0]);
    float xn = v / (norm + 1e-12f);
    ushort hi = f2bf(xn);
    xh[(size_t)n * HH + c] = hi;
    xl[(size_t)n * HH + c] = f2bf(xn - bf2f(hi));
}

// ---------------------------------------------------------------------------
// top-3 helpers (exact top_k tie-breaking: value desc, index asc)
// ---------------------------------------------------------------------------
__device__ __forceinline__ bool tk_better(float va, int ia, float vb, int ib)
{
    return (va > vb) || (va == vb && ia < ib);
}

__device__ __forceinline__ void ins3(float v, int i,
                                     float& a0, int& b0, float& a1, int& b1,
                                     float& a2, int& b2)
{
    if (tk_better(v, i, a0, b0))      { a2 = a1; b2 = b1; a1 = a0; b1 = b0; a0 = v; b0 = i; }
    else if (tk_better(v, i, a1, b1)) { a2 = a1; b2 = b1; a1 = v;  b1 = i; }
    else if (tk_better(v, i, a2, b2)) { a2 = v;  b2 = i; }
}

__device__ __forceinline__ void merge3(float& v0, float& v1, float& v2,
                                       int& i0, int& i1, int& i2, int off)
{
    float w0 = __shfl_xor(v0, off), w1 = __shfl_xor(v1, off), w2 = __shfl_xor(v2, off);
    int   j0 = __shfl_xor(i0, off), j1 = __shfl_xor(i1, off), j2 = __shfl_xor(i2, off);
    float avv[3] = { v0, v1, v2 }, bvv[3] = { w0, w1, w2 };
    int   aii[3] = { i0, i1, i2 }, bii[3] = { j0, j1, j2 };
    float rv[3]; int ri[3];
    int p = 0, q = 0;
    #pragma unroll
    for (int t = 0; t < 3; ++t) {
        bool takeA = tk_better(avv[p], aii[p], bvv[q], bii[q]);
        rv[t] = takeA ? avv[p] : bvv[q];
        ri[t] = takeA ? aii[p] : bii[q];
        if (takeA) ++p; else ++q;
    }
    v0 = rv[0]; v1 = rv[1]; v2 = rv[2];
    i0 = ri[0]; i1 = ri[1]; i2 = ri[2];
}

// ---------------------------------------------------------------------------
// simtopk v5: HIGH OCCUPANCY (latency-hiding via TLP).
// Block = 64 rows of one graph, 4 waves; wave owns 16 rows x 128 cols.
// BK=32 chunks; LDS only ~31KB (rows padded to 40 ushorts = 80B stride ->
// bank pattern repeats every 8 rows -> 2-way aliasing = free, no swizzle).
// ~4 blocks/CU -> ALL 832 blocks resident: other blocks' MFMA covers each
// phase's staging latency (rounds 4-9 had 2 blocks/CU and sat 95% idle).
// ---------------------------------------------------------------------------
__global__ __launch_bounds__(256)
void simtopk(const ushort* __restrict__ xnh, const ushort* __restrict__ xnl,
             int* __restrict__ fsrc)
{
    __shared__ ushort Ash[64][40], Asl[64][40];     // 10.2 KB
    __shared__ ushort Bsh[128][40], Bsl[128][40];   // 20.5 KB
    const int bid = blockIdx.x;
    const int xcd = bid & 7;
    const int rb  = (bid >> 3) & 7;
    const int g   = (bid >> 6) * 8 + xcd;
    if (g >= GG) return;
    const int row0 = rb * 64;
    const int tid  = threadIdx.x;
    const int lane = tid & 63;
    const int w    = tid >> 6;
    const int lr   = lane & 15;
    const int hi4  = lane >> 4;
    const int lk   = hi4 * 8;
    const size_t base = (size_t)g * NPGc * HH;

    // running top-3 per acc row r: rows row0 + w*16 + hi4*4 + r
    float tv0[4], tv1[4], tv2[4];
    int   ti0[4], ti1[4], ti2[4];
    #pragma unroll
    for (int r = 0; r < 4; ++r) {
        tv0[r] = tv1[r] = tv2[r] = -2.f;
        ti0[r] = ti1[r] = ti2[r] = 0x7fffffff;
    }

    // staging coords (fixed per thread)
    const int sArow = tid >> 2, sAc8 = (tid & 3) * 8;   // A: 1 granule/thread
    for (int ct = 0; ct < 4; ++ct) {
        const int col0 = ct * 128;
        f32x4 acc[8] = {};
        for (int k0 = 0; k0 < HH; k0 += 32) {
            __syncthreads();
            {   // stage A: 64 rows x 32 k (hi+lo)
                int grow = row0 + sArow; if (grow > NPGc - 1) grow = NPGc - 1;
                size_t o = base + (size_t)grow * HH + k0 + sAc8;
                *(int4*)&Ash[sArow][sAc8] = *(const int4*)(xnh + o);
                *(int4*)&Asl[sArow][sAc8] = *(const int4*)(xnl + o);
            }
            #pragma unroll
            for (int it = 0; it < 2; ++it) {  // stage B: 128 cols x 32 k (hi+lo)
                int flat = it * 256 + tid;
                int row = flat >> 2, c8 = (flat & 3) * 8;
                int gcol = col0 + row; if (gcol > NPGc - 1) gcol = NPGc - 1;
                size_t o = base + (size_t)gcol * HH + k0 + c8;
                *(int4*)&Bsh[row][c8] = *(const int4*)(xnh + o);
                *(int4*)&Bsl[row][c8] = *(const int4*)(xnl + o);
            }
            __syncthreads();
            const int ra = w * 16 + lr;
            short8v ah = *(const short8v*)&Ash[ra][lk];
            short8v al = *(const short8v*)&Asl[ra][lk];
            #pragma unroll
            for (int n = 0; n < 8; ++n) {
                const int rbn = n * 16 + lr;
                short8v bh = *(const short8v*)&Bsh[rbn][lk];
                short8v bl = *(const short8v*)&Bsl[rbn][lk];
                acc[n] = __builtin_amdgcn_mfma_f32_16x16x32_bf16(ah, bh, acc[n], 0, 0, 0);
                acc[n] = __builtin_amdgcn_mfma_f32_16x16x32_bf16(ah, bl, acc[n], 0, 0, 0);
                acc[n] = __builtin_amdgcn_mfma_f32_16x16x32_bf16(al, bh, acc[n], 0, 0, 0);
            }
        }
        // fold this col-tile into running top-3, scalar locals per row r
        #pragma unroll
        for (int r = 0; r < 4; ++r) {
            float a0 = tv0[r], a1 = tv1[r], a2 = tv2[r];
            int   b0 = ti0[r], b1 = ti1[r], b2 = ti2[r];
            #pragma unroll
            for (int n = 0; n < 8; ++n) {
                int col = col0 + n * 16 + lr;
                if (col < NPGc)
                    ins3(acc[n][r], col, a0, b0, a1, b1, a2, b2);
            }
            tv0[r] = a0; tv1[r] = a1; tv2[r] = a2;
            ti0[r] = b0; ti1[r] = b1; ti2[r] = b2;
        }
    }

    // merge across the 16 lanes sharing each row-quad (xor 1,2,4,8), then write
    #pragma unroll
    for (int r = 0; r < 4; ++r) {
        float a0 = tv0[r], a1 = tv1[r], a2 = tv2[r];
        int   b0 = ti0[r], b1 = ti1[r], b2 = ti2[r];
        #pragma unroll
        for (int off = 1; off <= 8; off <<= 1)
            merge3(a0, a1, a2, b0, b1, b2, off);
        if (lr == 0) {
            int row = row0 + w * 16 + hi4 * 4 + r;
            if (row < NPGc) {
                int rg = g * NPGc + row;
                fsrc[rg * 3 + 0] = g * NPGc + b0;
                fsrc[rg * 3 + 1] = g * NPGc + b1;
                fsrc[rg * 3 + 2] = g * NPGc + b2;
            }
        }
    }
}

// ---------------------------------------------------------------------------
// CSR build
// ---------------------------------------------------------------------------
__global__ void hist_kernel(const int* __restrict__ dst, int* __restrict__ cnt, int nE)
{
    int e = blockIdx.x * 256 + threadIdx.x;
    if (e < nE) atomicAdd(&cnt[dst[e]], 1);
}

__global__ void scan1_kernel(const int* __restrict__ in, int* __restrict__ out,
                             int* __restrict__ bsum, int n)
{
    __shared__ int sh[256];
    int t = threadIdx.x;
    int i = blockIdx.x * 256 + t;
    int v = (i < n) ? in[i] : 0;
    sh[t] = v;
    __syncthreads();
    for (int s = 1; s < 256; s <<= 1) {
        int tv = (t >= s) ? sh[t - s] : 0;
        __syncthreads();
        sh[t] += tv;
        __syncthreads();
    }
    if (i < n) out[i] = sh[t] - v;  // exclusive
    if (t == 255) bsum[blockIdx.x] = sh[255];
}

__global__ void scan2_kernel(int* __restrict__ bsum, int nb)
{
    __shared__ int sh[256];
    int t = threadIdx.x;
    int v = (t < nb) ? bsum[t] : 0;
    sh[t] = v;
    __syncthreads();
    for (int s = 1; s < 256; s <<= 1) {
        int tv = (t >= s) ? sh[t - s] : 0;
        __syncthreads();
        sh[t] += tv;
        __syncthreads();
    }
    if (t < nb) bsum[t] = sh[t] - v;  // exclusive block offsets
}

__global__ void scan3_kernel(int* __restrict__ out, const int* __restrict__ bsum, int n)
{
    int i = blockIdx.x * 256 + threadIdx.x;
    if (i < n) out[i] += bsum[blockIdx.x];
}

__global__ void fill_kernel(const int* __restrict__ src, const int* __restrict__ dst,
                            const int* __restrict__ row_ptr, int* __restrict__ cursor,
                            int* __restrict__ sorted_src, int nE)
{
    int e = blockIdx.x * 256 + threadIdx.x;
    if (e < nE) {
        int d = dst[e];
        int pos = row_ptr[d] + atomicAdd(&cursor[d], 1);
        sorted_src[pos] = src[e];
    }
}

__global__ void dinv_kernel(const int* __restrict__ cnt, float* __restrict__ dinv, int n)
{
    int i = blockIdx.x * 256 + threadIdx.x;
    if (i < n) dinv[i] = rsqrtf((float)cnt[i] + 1.0f);
}

// ---------------------------------------------------------------------------
// GCN gather (bf16 messages, XCD-bijective swizzle: graph g -> XCD g%8)
// grid = 8 * 13 * 500 = 52000, blocks with g >= 100 exit.
// ---------------------------------------------------------------------------
__global__ __launch_bounds__(256)
void gcn_gather(const ushort* __restrict__ m, const int* __restrict__ row_ptr,
                const int* __restrict__ cnt, const int* __restrict__ srcs,
                const float* __restrict__ dinv, const float* __restrict__ bias,
                float* __restrict__ out)
{
    int bid = blockIdx.x;
    int xcd = bid & 7, idx = bid >> 3;
    int g = xcd + 8 * (idx / NPGc);
    if (g >= GG) return;
    int n = g * NPGc + (idx % NPGc);
    int c = threadIdx.x;
    float dn = dinv[n];
    float acc = bf2f(m[(size_t)n * HH + c]) * dn;
    int s0 = row_ptr[n], e0 = s0 + cnt[n];
    for (int e = s0; e < e0; ++e) {
        int s = srcs[e];
        acc += bf2f(m[(size_t)s * HH + c]) * dinv[s];
    }
    out[(size_t)n * HH + c] = acc * dn + bias[c];
}

// knn-graph conv: all degrees are K+1=4 -> coef = 0.25 everywhere
__global__ __launch_bounds__(256)
void fgcn_gather(const ushort* __restrict__ m, const int* __restrict__ fsrc,
                 const float* __restrict__ bias, float* __restrict__ out)
{
    int bid = blockIdx.x;
    int xcd = bid & 7, idx = bid >> 3;
    int g = xcd + 8 * (idx / NPGc);
    if (g >= GG) return;
    int n = g * NPGc + (idx % NPGc);
    int c = threadIdx.x;
    int s0 = fsrc[n * 3], s1 = fsrc[n * 3 + 1], s2 = fsrc[n * 3 + 2];
    float acc = bf2f(m[(size_t)n * HH + c]) + bf2f(m[(size_t)s0 * HH + c])
              + bf2f(m[(size_t)s1 * HH + c]) + bf2f(m[(size_t)s2 * HH + c]);
    out[(size_t)n * HH + c] = 0.25f * acc + bias[c];
}

// ---------------------------------------------------------------------------
// GraphNorm
// ---------------------------------------------------------------------------
__global__ __launch_bounds__(256)
void norm_stats(const float* __restrict__ x, float* __restrict__ S1, float* __restrict__ S2)
{
    int g = blockIdx.x, chunk = blockIdx.y, c = threadIdx.x;
    int r0 = chunk * 63, r1 = min(r0 + 63, NPGc);
    float s1 = 0.f, s2 = 0.f;
    for (int r = r0; r < r1; ++r) {
        float v = x[((size_t)(g * NPGc + r)) * HH + c];
        s1 += v; s2 += v * v;
    }
    atomicAdd(&S1[g * HH + c], s1);
    atomicAdd(&S2[g * HH + c], s2);
}

__global__ __launch_bounds__(256)
void norm_apply(float* __restrict__ x, const float* __restrict__ S1, const float* __restrict__ S2,
                const float* __restrict__ w, const float* __restrict__ b,
                const float* __restrict__ ms)
{
    int n = blockIdx.x, c = threadIdx.x;
    int g = n / NPGc;
    size_t o = (size_t)n * HH + c;
    float v = x[o];
    float mean = S1[g * HH + c] / (float)NPGc;
    float mm = mean * ms[c];
    float var = S2[g * HH + c] / (float)NPGc - 2.f * mm * mean + mm * mm;
    float outv = w[c] * (v - mm) * rsqrtf(var + 1e-5f) + b[c];
    x[o] = outv > 0.f ? outv : 0.01f * outv;
}

// ---------------------------------------------------------------------------
// Pool: gf[g] = (sum X0 + 2*sum X1) / 500   (all_x[-1]==all_x[1] quirk)
// ---------------------------------------------------------------------------
__global__ __launch_bounds__(256)
void pool_kernel(const float* __restrict__ X0, const float* __restrict__ X1,
                 float* __restrict__ out)
{
    int g = blockIdx.x, c = threadIdx.x;
    float s0 = 0.f, s1 = 0.f;
    for (int r = 0; r < NPGc; ++r) {
        size_t o = ((size_t)(g * NPGc + r)) * HH + c;
        s0 += X0[o];
        s1 += X1[o];
    }
    out[g * HH + c] = (s0 + 2.f * s1) / (float)NPGc;
}

__global__ void sentinel_kernel(float* out, int n)
{
    int i = blockIdx.x * 256 + threadIdx.x;
    if (i < n) out[i] = 12345.0f;
}

// ---------------------------------------------------------------------------
extern "C" void kernel_launch(void* const* d_in, const int* in_sizes, int n_in,
                              void* d_out, int out_size, void* d_ws, size_t ws_size,
                              hipStream_t stream)
{
    const float* x       = (const float*)d_in[0];
    const int* edge_idx  = (const int*)d_in[1];
    const float* emb_W   = (const float*)d_in[3];
    const float* emb_b   = (const float*)d_in[4];
    const float* conv_W  = (const float*)d_in[5];
    const float* conv_b  = (const float*)d_in[6];
    const float* fconv_W = (const float*)d_in[7];
    const float* fconv_b = (const float*)d_in[8];
    const float* norm_w  = (const float*)d_in[9];
    const float* norm_b  = (const float*)d_in[10];
    const float* norm_ms = (const float*)d_in[11];
    const float* fnorm_w = (const float*)d_in[12];
    const float* fnorm_b = (const float*)d_in[13];
    const float* fnorm_ms= (const float*)d_in[14];
    const float* gate_W  = (const float*)d_in[15];
    const float* gate_b  = (const float*)d_in[16];

    const int E = in_sizes[1] / 2;
    const int* esrc = edge_idx;
    const int* edst = edge_idx + E;

    const size_t NHf = (size_t)NN * HH;           // 12.8M elements
    char* p = (char*)d_ws;
    auto alloc = [&](size_t bytes) { char* r = p; p += (bytes + 255) & ~(size_t)255; return r; };
    float* B0 = (float*)alloc(NHf * 4);
    float* B1 = (float*)alloc(NHf * 4);
    float* B2 = (float*)alloc(NHf * 4);
    float* B3 = (float*)alloc(NHf * 4);
    ushort* xnh = (ushort*)B2;          // 25.6MB overlay, dead once layers start
    ushort* xnl = xnh + NHf;            // 25.6MB (rest of B2)
    ushort* msgbf = (ushort*)alloc(NHf * 2);  // bf16 message buffer
    int* sorted_src = (int*)alloc((size_t)E * 4);
    int* row_ptr    = (int*)alloc((size_t)NN * 4);
    int* deg_cnt    = (int*)alloc((size_t)NN * 4);
    int* cursor     = (int*)alloc((size_t)NN * 4);
    float* dinv     = (float*)alloc((size_t)NN * 4);
    int* fsrc       = (int*)alloc((size_t)NN * 3 * 4);
    float* S1       = (float*)alloc((size_t)GG * HH * 4);
    float* S2       = (float*)alloc((size_t)GG * HH * 4);
    int* bsum       = (int*)alloc(1024);
    ushort* wts     = (ushort*)alloc((size_t)425984 * 2);  // all W^T bf16
    size_t needed = (size_t)(p - (char*)d_ws);
    if (ws_size < needed) {
        sentinel_kernel<<<(out_size + 255) / 256, 256, 0, stream>>>((float*)d_out, out_size);
        return;
    }
    ushort* embWt   = wts;                    // [256][128]
    ushort* convWt0 = wts + 32768;            // [256][256]
    ushort* convWt1 = wts + 32768 + 65536;
    ushort* fconvWt0 = wts + 163840;
    ushort* fconvWt1 = wts + 163840 + 65536;
    ushort* gateWt  = wts + 294912;           // [256][512]

    const int nScanB = (NN + 255) / 256;  // 196
    const int gatherGrid = 8 * 13 * NPGc; // 52000 (XCD-bijective, skip g>=100)

    hipMemsetAsync(deg_cnt, 0, (size_t)NN * 4, stream);
    hipMemsetAsync(cursor, 0, (size_t)NN * 4, stream);

    // 0. weight transpose+cvt
    wcvt<<<(32768 + 255) / 256, 256, 0, stream>>>(emb_W, embWt, IND, HH);
    wcvt<<<(65536 + 255) / 256, 256, 0, stream>>>(conv_W, convWt0, HH, HH);
    wcvt<<<(65536 + 255) / 256, 256, 0, stream>>>(conv_W + 65536, convWt1, HH, HH);
    wcvt<<<(65536 + 255) / 256, 256, 0, stream>>>(fconv_W, fconvWt0, HH, HH);
    wcvt<<<(65536 + 255) / 256, 256, 0, stream>>>(fconv_W + 65536, fconvWt1, HH, HH);
    wcvt<<<(131072 + 255) / 256, 256, 0, stream>>>(gate_W, gateWt, 2 * HH, HH);

    // 1. embedding: h0 = x @ emb_W + emb_b -> B0
    dim3 ggrid((NN + 127) / 128, 2);
    gemm_mfma<<<ggrid, 256, 0, stream>>>(x, nullptr, embWt, emb_b, B0, nullptr,
                                         NN, IND, IND, 0, nullptr, nullptr, nullptr);

    // 2. CSR of edge_index by dst
    hist_kernel<<<(E + 255) / 256, 256, 0, stream>>>(edst, deg_cnt, E);
    scan1_kernel<<<nScanB, 256, 0, stream>>>(deg_cnt, row_ptr, bsum, NN);
    scan2_kernel<<<1, 256, 0, stream>>>(bsum, nScanB);
    scan3_kernel<<<nScanB, 256, 0, stream>>>(row_ptr, bsum, NN);
    fill_kernel<<<(E + 255) / 256, 256, 0, stream>>>(esrc, edst, row_ptr, cursor, sorted_src, E);
    dinv_kernel<<<(NN + 255) / 256, 256, 0, stream>>>(deg_cnt, dinv, NN);

    // 3. knn graph from h0 (hi/lo split, high-occupancy fused sim+topk)
    row_norm_hl<<<NN, 256, 0, stream>>>(B0, xnh, xnl);
    simtopk<<<832, 256, 0, stream>>>(xnh, xnl, fsrc);

    // 4. layers
    float* h  = B0;
    float* mb = B1;
    dim3 ngrid(GG, 8);
    for (int i = 0; i < 2; ++i) {
        const ushort* Wc = (i == 0) ? convWt0 : convWt1;
        const ushort* Wf = (i == 0) ? fconvWt0 : fconvWt1;
        const float* bc  = conv_b  + (size_t)i * HH;
        const float* bf  = fconv_b + (size_t)i * HH;
        // h-road conv -> bf16 messages
        gemm_mfma<<<ggrid, 256, 0, stream>>>(h, nullptr, Wc, nullptr, nullptr, msgbf,
                                             NN, HH, HH, 2, nullptr, nullptr, nullptr);
        gcn_gather<<<gatherGrid, 256, 0, stream>>>(msgbf, row_ptr, deg_cnt, sorted_src,
                                                   dinv, bc, B2);
        hipMemsetAsync(S1, 0, (size_t)2 * GG * HH * 4, stream);
        norm_stats<<<ngrid, 256, 0, stream>>>(B2, S1, S2);
        norm_apply<<<NN, 256, 0, stream>>>(B2, S1, S2, norm_w + i * HH, norm_b + i * HH,
                                           norm_ms + i * HH);
        // f-road conv (knn graph) -> bf16 messages
        gemm_mfma<<<ggrid, 256, 0, stream>>>(B2, nullptr, Wf, nullptr, nullptr, msgbf,
                                             NN, HH, HH, 2, nullptr, nullptr, nullptr);
        fgcn_gather<<<gatherGrid, 256, 0, stream>>>(msgbf, fsrc, bf, B3);
        hipMemsetAsync(S1, 0, (size_t)2 * GG * HH * 4, stream);
        norm_stats<<<ngrid, 256, 0, stream>>>(B3, S1, S2);
        norm_apply<<<NN, 256, 0, stream>>>(B3, S1, S2, fnorm_w + i * HH, fnorm_b + i * HH,
                                           fnorm_ms + i * HH);
        // gate + combine
        gemm_mfma<<<ggrid, 256, 0, stream>>>(B2, B3, gateWt, gate_b, mb, nullptr,
                                             NN, 2 * HH, HH, 1, B2, B3, h);
        float* t = h; h = mb; mb = t;
    }
    // h = all_x[1], mb = all_x[0]
    pool_kernel<<<GG, 256, 0, stream>>>(mb, h, (float*)d_out);
}